// Round 1
// baseline (998.729 us; speedup 1.0000x reference)
//
#include <hip/hip_runtime.h>

// ConventionalGNN: 3x (GCNConv -> GraphNorm -> ReLU), N=100000 nodes, E=1.6M edges, D=128.
// Strategy: build CSR (by dst) once per call, then per layer: GEMM -> CSR gather -> stats -> norm.

#define EPS_GN 1e-5f

// ---------------- CSR build ----------------

__global__ __launch_bounds__(256) void k_count(const int* __restrict__ dst,
                                               int* __restrict__ cnt, int E) {
  int e = blockIdx.x * 256 + threadIdx.x;
  if (e < E) atomicAdd(&cnt[dst[e]], 1);
}

// Block-level exclusive scan, 1024 elems/block (4 per thread).
__global__ __launch_bounds__(256) void k_scan1(const int* __restrict__ cnt,
                                               int* __restrict__ rs,
                                               int* __restrict__ bsum, int N) {
  __shared__ int s[256];
  int t = threadIdx.x;
  int base = blockIdx.x * 1024 + t * 4;
  int c0 = (base + 0 < N) ? cnt[base + 0] : 0;
  int c1 = (base + 1 < N) ? cnt[base + 1] : 0;
  int c2 = (base + 2 < N) ? cnt[base + 2] : 0;
  int c3 = (base + 3 < N) ? cnt[base + 3] : 0;
  int tsum = c0 + c1 + c2 + c3;
  s[t] = tsum;
  __syncthreads();
  for (int off = 1; off < 256; off <<= 1) {
    int v = (t >= off) ? s[t - off] : 0;
    __syncthreads();
    s[t] += v;
    __syncthreads();
  }
  int excl = s[t] - tsum;
  if (t == 255) bsum[blockIdx.x] = s[255];
  int e0 = excl, e1 = e0 + c0, e2 = e1 + c1, e3 = e2 + c2;
  if (base + 0 < N) rs[base + 0] = e0;
  if (base + 1 < N) rs[base + 1] = e1;
  if (base + 2 < N) rs[base + 2] = e2;
  if (base + 3 < N) rs[base + 3] = e3;
}

__global__ __launch_bounds__(256) void k_scan2(const int* __restrict__ bsum,
                                               int* __restrict__ boff, int nblk) {
  __shared__ int s[256];
  int t = threadIdx.x;
  int v0 = (t < nblk) ? bsum[t] : 0;
  s[t] = v0;
  __syncthreads();
  for (int off = 1; off < 256; off <<= 1) {
    int v = (t >= off) ? s[t - off] : 0;
    __syncthreads();
    s[t] += v;
    __syncthreads();
  }
  if (t < nblk) boff[t] = s[t] - v0;
}

__global__ __launch_bounds__(256) void k_finalize(const int* __restrict__ cnt,
                                                  const int* __restrict__ boff,
                                                  int* __restrict__ rs,
                                                  int* __restrict__ cursor,
                                                  float* __restrict__ dinv, int N, int E) {
  int i = blockIdx.x * 256 + threadIdx.x;
  if (i == 0) rs[N] = E;
  if (i < N) {
    int v = rs[i] + boff[i >> 10];
    rs[i] = v;
    cursor[i] = v;
    dinv[i] = rsqrtf((float)cnt[i] + 1.0f);
  }
}

__global__ __launch_bounds__(256) void k_fill(const int* __restrict__ src,
                                              const int* __restrict__ dst,
                                              const float* __restrict__ dinv,
                                              int* __restrict__ cursor,
                                              int* __restrict__ csr_src,
                                              float* __restrict__ csr_coef, int E) {
  int e = blockIdx.x * 256 + threadIdx.x;
  if (e >= E) return;
  int s = src[e], d = dst[e];
  int p = atomicAdd(&cursor[d], 1);
  csr_src[p] = s;
  csr_coef[p] = dinv[s] * dinv[d];
}

// ---------------- Layer kernels ----------------

// H = X @ W0, X:[N,4], W0:[4,128]. 2 rows per block of 256.
__global__ __launch_bounds__(256) void k_gemm0(const float* __restrict__ X,
                                               const float* __restrict__ W,
                                               float* __restrict__ H, int N) {
  __shared__ float Ws[4 * 128];
  int t = threadIdx.x;
  if (t < 128) {
    Ws[t] = W[t];
    Ws[128 + t] = W[128 + t];
    Ws[256 + t] = W[256 + t];
    Ws[384 + t] = W[384 + t];
  }
  __syncthreads();
  int col = t & 127, half = t >> 7;
  int row = blockIdx.x * 2 + half;
  if (row >= N) return;
  float4 xv = ((const float4*)X)[row];
  float v = xv.x * Ws[col] + xv.y * Ws[128 + col] + xv.z * Ws[256 + col] + xv.w * Ws[384 + col];
  H[(size_t)row * 128 + col] = v;
}

// H = X @ W, X:[N,128], W:[128,128]. Block: 16 rows x 128 cols; thread = 1 row x 8 cols
// (two float4 at cg*4 and 64+cg*4 => conflict-light b128 LDS reads, coalesced stores).
__global__ __launch_bounds__(256) void k_gemm128(const float* __restrict__ X,
                                                 const float* __restrict__ W,
                                                 float* __restrict__ H, int N) {
  __shared__ float4 Ws4[128 * 32];  // 64 KiB: W row-major as float4
  int t = threadIdx.x;
  const float4* W4 = (const float4*)W;
#pragma unroll
  for (int i = 0; i < 16; ++i) Ws4[t + i * 256] = W4[t + i * 256];
  __syncthreads();
  int rg = t >> 4, cg = t & 15;
  int row = blockIdx.x * 16 + rg;
  if (row >= N) return;
  const float4* X4 = (const float4*)(X + (size_t)row * 128);
  float a0x = 0, a0y = 0, a0z = 0, a0w = 0;
  float a1x = 0, a1y = 0, a1z = 0, a1w = 0;
#pragma unroll 4
  for (int k4 = 0; k4 < 32; ++k4) {
    float4 xv = X4[k4];
    float xs[4] = {xv.x, xv.y, xv.z, xv.w};
#pragma unroll
    for (int j = 0; j < 4; ++j) {
      int k = k4 * 4 + j;
      float4 w0 = Ws4[k * 32 + cg];
      float4 w1 = Ws4[k * 32 + 16 + cg];
      float xsj = xs[j];
      a0x = fmaf(xsj, w0.x, a0x);
      a0y = fmaf(xsj, w0.y, a0y);
      a0z = fmaf(xsj, w0.z, a0z);
      a0w = fmaf(xsj, w0.w, a0w);
      a1x = fmaf(xsj, w1.x, a1x);
      a1y = fmaf(xsj, w1.y, a1y);
      a1z = fmaf(xsj, w1.z, a1z);
      a1w = fmaf(xsj, w1.w, a1w);
    }
  }
  float4* H4 = (float4*)(H + (size_t)row * 128);
  H4[cg] = make_float4(a0x, a0y, a0z, a0w);
  H4[16 + cg] = make_float4(a1x, a1y, a1z, a1w);
}

// AGG[n] = H[n]*dinv[n]^2 + sum_{e: dst=n} H[src[e]] * coef[e]. One wave per node.
__global__ __launch_bounds__(256) void k_gather(const float* __restrict__ H,
                                                const int* __restrict__ rs,
                                                const int* __restrict__ csr_src,
                                                const float* __restrict__ csr_coef,
                                                const float* __restrict__ dinv,
                                                float* __restrict__ AGG, int N) {
  int wave = threadIdx.x >> 6, lane = threadIdx.x & 63;
  int n = blockIdx.x * 4 + wave;
  if (n >= N) return;
  const float2* H2 = (const float2*)H;
  float di = dinv[n];
  float selfc = di * di;
  float2 acc = H2[(size_t)n * 64 + lane];
  acc.x *= selfc;
  acc.y *= selfc;
  int j0 = rs[n], j1 = rs[n + 1];
  if (j0 < j1) {
    int s = csr_src[j0];
    float c = csr_coef[j0];
    float2 hv = H2[(size_t)s * 64 + lane];
    for (int j = j0 + 1; j < j1; ++j) {
      int s2 = csr_src[j];
      float c2 = csr_coef[j];
      float2 hv2 = H2[(size_t)s2 * 64 + lane];  // issue next load before consuming current
      acc.x = fmaf(hv.x, c, acc.x);
      acc.y = fmaf(hv.y, c, acc.y);
      hv = hv2;
      c = c2;
    }
    acc.x = fmaf(hv.x, c, acc.x);
    acc.y = fmaf(hv.y, c, acc.y);
  }
  ((float2*)AGG)[(size_t)n * 64 + lane] = acc;
}

// Column sums of (X + bias): stats[c] = sum, stats[128+c] = sumsq.
__global__ __launch_bounds__(256) void k_stats(const float* __restrict__ X,
                                               const float* __restrict__ bias,
                                               float* __restrict__ stats, int N) {
  int t = threadIdx.x;
  int col = t & 127, half = t >> 7;
  float b = bias[col];
  float s1 = 0.f, s2 = 0.f;
  for (int r = blockIdx.x * 2 + half; r < N; r += gridDim.x * 2) {
    float v = X[(size_t)r * 128 + col] + b;
    s1 += v;
    s2 = fmaf(v, v, s2);
  }
  __shared__ float sh[512];
  sh[t] = s1;
  sh[256 + t] = s2;
  __syncthreads();
  if (t < 128) {
    float a1 = sh[t] + sh[t + 128];
    float a2 = sh[256 + t] + sh[256 + t + 128];
    atomicAdd(&stats[col], a1);
    atomicAdd(&stats[128 + col], a2);
  }
}

// OUT = relu(A*agg + B) with A,B derived per-column from stats (+ bias/gamma/beta/alpha fold).
__global__ __launch_bounds__(256) void k_norm(const float* __restrict__ AGG,
                                              const float* __restrict__ stats,
                                              const float* __restrict__ bias,
                                              const float* __restrict__ gamma,
                                              const float* __restrict__ beta,
                                              const float* __restrict__ alpha,
                                              float* __restrict__ OUT, int N, float invN) {
  int i = blockIdx.x * 256 + threadIdx.x;  // float4 index
  if (i >= N * 32) return;
  int c4 = i & 31;
  float4 v = ((const float4*)AGG)[i];
  float vv[4] = {v.x, v.y, v.z, v.w};
  float ov[4];
#pragma unroll
  for (int j = 0; j < 4; ++j) {
    int c = c4 * 4 + j;
    float mu = stats[c] * invN;
    float E2 = stats[128 + c] * invN;
    float a = alpha[c], g = gamma[c], be = beta[c], b = bias[c];
    float var = E2 - (2.0f * a - a * a) * mu * mu;
    float A = g * rsqrtf(var + EPS_GN);
    float B = be - A * a * mu + A * b;
    float o = fmaf(A, vv[j], B);
    ov[j] = o > 0.f ? o : 0.f;
  }
  ((float4*)OUT)[i] = make_float4(ov[0], ov[1], ov[2], ov[3]);
}

// ---------------- Launch ----------------

extern "C" void kernel_launch(void* const* d_in, const int* in_sizes, int n_in,
                              void* d_out, int out_size, void* d_ws, size_t ws_size,
                              hipStream_t stream) {
  const float* x = (const float*)d_in[0];
  const int* ei = (const int*)d_in[1];
  const float* W0 = (const float*)d_in[2];
  const float* b0 = (const float*)d_in[3];
  const float* W12 = (const float*)d_in[4];
  const float* b12 = (const float*)d_in[5];
  const float* gamma = (const float*)d_in[6];
  const float* beta = (const float*)d_in[7];
  const float* alpha = (const float*)d_in[8];
  float* out = (float*)d_out;

  int N = in_sizes[0] / 4;
  int E = in_sizes[1] / 2;
  const int* srcArr = ei;
  const int* dstArr = ei + E;

  char* w = (char*)d_ws;
  auto alloc = [&](size_t bytes) {
    char* p = w;
    w += (bytes + 255) & ~(size_t)255;
    return p;
  };
  int* cnt = (int*)alloc((size_t)N * 4);
  float* stats = (float*)alloc(3 * 256 * 4);  // [layer][sum(128)|sumsq(128)]
  int* rs = (int*)alloc(((size_t)N + 1) * 4);
  int* cursor = (int*)alloc((size_t)N * 4);
  int* bsum = (int*)alloc(512);
  int* boff = (int*)alloc(512);
  int* csr_src = (int*)alloc((size_t)E * 4);
  float* csr_coef = (float*)alloc((size_t)E * 4);
  float* dinv = (float*)alloc((size_t)N * 4);
  float* P = (float*)alloc((size_t)N * 128 * 4);

  // zero cnt + all stats (contiguous region)
  size_t zlen = (size_t)((char*)stats - (char*)cnt) + 3 * 256 * 4;
  hipMemsetAsync(cnt, 0, zlen, stream);

  int nblk = (N + 1023) / 1024;
  k_count<<<(E + 255) / 256, 256, 0, stream>>>(dstArr, cnt, E);
  k_scan1<<<nblk, 256, 0, stream>>>(cnt, rs, bsum, N);
  k_scan2<<<1, 256, 0, stream>>>(bsum, boff, nblk);
  k_finalize<<<(N + 255) / 256, 256, 0, stream>>>(cnt, boff, rs, cursor, dinv, N, E);
  k_fill<<<(E + 255) / 256, 256, 0, stream>>>(srcArr, dstArr, dinv, cursor, csr_src, csr_coef, E);

  float* Q = out;
  float invN = 1.0f / (float)N;
  int gGather = (N + 3) / 4;
  int gNorm = (N * 32 + 255) / 256;

  // Layer 0: x(P<-gemm0), gather P->Q, stats(Q), norm Q->P
  k_gemm0<<<(N + 1) / 2, 256, 0, stream>>>(x, W0, P, N);
  k_gather<<<gGather, 256, 0, stream>>>(P, rs, csr_src, csr_coef, dinv, Q, N);
  k_stats<<<1024, 256, 0, stream>>>(Q, b0, stats, N);
  k_norm<<<gNorm, 256, 0, stream>>>(Q, stats, b0, gamma, beta, alpha, P, N, invN);

  // Layer 1: gemm P->Q, gather Q->P, stats(P), norm P->Q
  k_gemm128<<<(N + 15) / 16, 256, 0, stream>>>(P, W12, Q, N);
  k_gather<<<gGather, 256, 0, stream>>>(Q, rs, csr_src, csr_coef, dinv, P, N);
  k_stats<<<1024, 256, 0, stream>>>(P, b12, stats + 256, N);
  k_norm<<<gNorm, 256, 0, stream>>>(P, stats + 256, b12, gamma + 128, beta + 128, alpha + 128, Q, N,
                                    invN);

  // Layer 2: gemm Q->P, gather P->Q(=out), stats(Q), norm in-place Q->Q
  k_gemm128<<<(N + 15) / 16, 256, 0, stream>>>(Q, W12 + 16384, P, N);
  k_gather<<<gGather, 256, 0, stream>>>(P, rs, csr_src, csr_coef, dinv, Q, N);
  k_stats<<<1024, 256, 0, stream>>>(Q, b12 + 128, stats + 512, N);
  k_norm<<<gNorm, 256, 0, stream>>>(Q, stats + 512, b12 + 128, gamma + 256, beta + 256, alpha + 256,
                                    Q, N, invN);
}